// Round 16
// baseline (558.231 us; speedup 1.0000x reference)
//
#include <hip/hip_runtime.h>
#include <hip/hip_bf16.h>

#define BN 4
#define DIM 64
#define NHEADS 8
#define HH 256
#define WH 256
#define NP (HH*WH)      // 65536
#define HF 512
#define WF 512

#define PD 258                       // padded dim
#define PROW (PD*64)                 // shorts per padded row
#define PPLANE ((size_t)PD*PD*64)    // shorts per padded plane

typedef __attribute__((ext_vector_type(8))) short bfx8;           // 8 bf16
typedef __attribute__((ext_vector_type(8))) unsigned short u16x8; // 8 bf16 bits
typedef __attribute__((ext_vector_type(4))) unsigned short u16x4; // 4 bf16 bits
typedef __attribute__((ext_vector_type(4))) float f32x4;          // MFMA C/D frag

static __device__ __forceinline__ short f2bf(float f) {
    unsigned u = __float_as_uint(f);
    unsigned r = (u + 0x7FFFu + ((u >> 16) & 1u)) >> 16;   // RNE
    return (short)r;
}
static __device__ __forceinline__ float bfu(unsigned short u) {
    return __uint_as_float((unsigned)u << 16);
}

// ---------------- merged setup: ring-zero 16 planes + all weight repacks ----------------
__global__ __launch_bounds__(256) void k_setup(unsigned short* __restrict__ tiled16,
                                               const float* __restrict__ w_ho,
                                               const float* __restrict__ w_hc1,
                                               const float* __restrict__ w_hc2,
                                               const float* __restrict__ w_qkv,
                                               short* __restrict__ wrHO,
                                               short* __restrict__ wrHC1,
                                               short* __restrict__ wrHC2,
                                               short* __restrict__ wrQKV) {
    int bx = blockIdx.x, tid = threadIdx.x;
    if (bx < 16) {                        // pad-ring zero, 16 planes (12 TILED + 4 LLP)
        char* base = (char*)(tiled16 + (size_t)bx * PPLANE);
        const int ROWB = PROW * 2;
        for (int k = tid; k < 8224; k += 256) {
            char* dst;
            if (k < 2064) dst = base + (size_t)k * 16;
            else if (k < 4128) dst = base + (size_t)257 * ROWB + (size_t)(k - 2064) * 16;
            else if (k < 6176) { int r = (k - 4128) >> 3, s = (k - 4128) & 7;
                dst = base + (size_t)(r + 1) * ROWB + (size_t)s * 16; }
            else { int r = (k - 6176) >> 3, s = (k - 6176) & 7;
                dst = base + (size_t)(r + 1) * ROWB + 257 * 128 + (size_t)s * 16; }
            *(uint4*)dst = (uint4){0, 0, 0, 0};
        }
        return;
    }
    if (bx < 16 + 432 + 288) {            // 3x3 repacks: OIHW -> [g][tap][icb][oc][8]
        const float* w = (bx < 448) ? w_ho : w_hc1;
        short* wrep = (bx < 448) ? wrHO : wrHC1;
        int t = (bx - ((bx < 448) ? 16 : 448)) * 256 + tid;
        unsigned g   = (unsigned)t / 36864u;
        unsigned r1  = (unsigned)t % 36864u;
        unsigned tap = r1 / 4096u;
        unsigned r2  = r1 % 4096u;
        unsigned icb = r2 / 512u;
        unsigned r3  = r2 % 512u;
        unsigned oc  = r3 >> 3;
        unsigned j   = r3 & 7u;
        wrep[t] = f2bf(w[(((size_t)g * 64 + oc) * 64 + icb * 8u + j) * 9 + tap]);
        return;
    }
    if (bx < 16 + 432 + 288 + 32) {       // w_hc2 [64][128] -> [oct][icb][oc16][8]
        int t = (bx - 736) * 256 + tid;
        int j = t & 7, gr = t >> 3, o16 = gr & 15, X = gr >> 4;
        int icb = X % 16, oct = X / 16;
        wrHC2[t] = f2bf(w_hc2[(size_t)(oct * 16 + o16) * 128 + icb * 8 + j]);
        return;
    }
    {                                     // w_qkv [192][64] -> [oct][icb][oc16][8]
        int t = (bx - 768) * 256 + tid;
        int j = t & 7, gr = t >> 3, o16 = gr & 15, X = gr >> 4;
        int icb = X % 8, oct = X / 8;
        wrQKV[t] = f2bf(w_qkv[(size_t)(oct * 16 + o16) * 64 + icb * 8 + j]);
    }
}

// ---------------- DWT -> 4 padded-swizzled bf16 planes (LH/HL/HH in TILED, LL in LLP) ----------------
__global__ __launch_bounds__(256) void k_dwt(const float* __restrict__ x,
                                             unsigned short* __restrict__ tiled,
                                             unsigned short* __restrict__ llp) {
    __shared__ unsigned short lds[3 * 128 * 64] __attribute__((aligned(16)));
    const int tid = threadIdx.x;
    const int pid = blockIdx.x;              // 512 = 32 y-patches x 16 x-patches
    const int b = blockIdx.y;
    const int y0 = (pid >> 4) * 8, x0 = (pid & 15) * 16;
    const int quad = tid & 127;
    const int qy = quad >> 4, qx = quad & 15;
    const int gy = y0 + qy, gx = x0 + qx;
    const int ich = tid >> 7;                // 0/1
    unsigned short* llb = llp + (size_t)b * PPLANE + ((size_t)(gy + 1) * PD + (gx + 1)) * 64;

#pragma unroll 4
    for (int it = 0; it < 16; ++it) {
        int ic = it * 4 + ich * 2;           // handle ic, ic+1 (pair => b32 writes)
        unsigned g = (((unsigned)(ic >> 3)) + (unsigned)gx + 2u * (unsigned)gy) & 7u;
        unsigned swz = (unsigned)quad * 64 + (g << 3) + (unsigned)(ic & 7);
        unsigned pk[3], pll;
#pragma unroll
        for (int s = 0; s < 2; ++s) {
            const float* px = x + (((size_t)(b * 64 + ic + s) * HF) + 2 * gy) * WF + 2 * gx;
            float2 e0 = *(const float2*)px;
            float2 e1 = *(const float2*)(px + WF);
            float a = e0.x, bb = e0.y, c = e1.x, d = e1.y;
            unsigned ll = (unsigned short)f2bf(( a + bb + c + d) * 0.5f);
            unsigned lh = (unsigned short)f2bf((-a - bb + c + d) * 0.5f);
            unsigned hl = (unsigned short)f2bf((-a + bb - c + d) * 0.5f);
            unsigned hh = (unsigned short)f2bf(( a - bb - c + d) * 0.5f);
            if (s == 0) { pll = ll; pk[0] = lh; pk[1] = hl; pk[2] = hh; }
            else { pll |= ll << 16; pk[0] |= lh << 16; pk[1] |= hl << 16; pk[2] |= hh << 16; }
        }
        *(unsigned*)&lds[swz]          = pk[0];
        *(unsigned*)&lds[8192 + swz]   = pk[1];
        *(unsigned*)&lds[16384 + swz]  = pk[2];
        *(unsigned*)&llb[(g << 3) + (unsigned)(ic & 7)] = pll;
    }
    __syncthreads();
#pragma unroll
    for (int it = 0; it < 12; ++it) {
        int cch = tid + it * 256;            // 0..3071 (uint4 chunks)
        int p = cch >> 10, rem = cch & 1023;
        int row = rem >> 7, col = rem & 127;
        unsigned short* dst = tiled + ((size_t)(b * 3 + p) * PD + (y0 + row + 1)) * PROW
                                    + (size_t)(x0 + 1) * 64 + (size_t)col * 8;
        *(uint4*)dst = *(const uint4*)((const char*)lds + (size_t)cch * 16);
    }
}

// ---------------- merged grouped 3x3 convs (yh: g5=0..2 -> YH; t1: g5=3..4 -> T1T) ----------------
// 512 threads / 8 waves, 2 output rows per wave: 24 waves/CU at 41.5 KB LDS.
__global__ __launch_bounds__(512) void k_gconv3x3_mfma(const unsigned short* __restrict__ tiled,
                                                       const bfx8* __restrict__ wrHO,
                                                       const bfx8* __restrict__ wrHC1,
                                                       unsigned short* __restrict__ yh,
                                                       unsigned short* __restrict__ t1t) {
    __shared__ short lds_in[324 * 64] __attribute__((aligned(16)));
    const int tid = threadIdx.x;
    const int l = tid & 63, wv = tid >> 6;   // 8 waves
    const int tile = blockIdx.x;
    const int x0 = (tile & 15) * 16, y0 = (tile >> 4) * 16;
    const int g5 = blockIdx.y, b = blockIdx.z;
    const bool ispath_t1 = (g5 >= 3);
    const int g = ispath_t1 ? (g5 - 3) : g5;            // source plane index
    const bfx8* wr = ispath_t1 ? wrHC1 : wrHO;
    const unsigned short* src = tiled + (size_t)(b * 3 + g) * PPLANE;

    // stage 2592 uint4 chunks: 5 x 512 + tail 32
#pragma unroll
    for (int it = 0; it < 5; ++it) {
        int cch = it * 512 + tid;
        unsigned row = (unsigned)cch / 144u, col = (unsigned)cch % 144u;
        const unsigned short* ga = src + (size_t)(y0 + row) * PROW + (size_t)x0 * 64 + (size_t)col * 8;
        __builtin_amdgcn_global_load_lds(
            (const __attribute__((address_space(1))) void*)ga,
            (__attribute__((address_space(3))) void*)((char*)lds_in + (size_t)(it * 512 + wv * 64) * 16),
            16, 0, 0);
    }
    if (tid < 32) {
        int cch = 2560 + tid;
        unsigned row = (unsigned)cch / 144u, col = (unsigned)cch % 144u;
        const unsigned short* ga = src + (size_t)(y0 + row) * PROW + (size_t)x0 * 64 + (size_t)col * 8;
        *(uint4*)((char*)lds_in + (size_t)cch * 16) = *(const uint4*)ga;
    }
    __syncthreads();

    f32x4 acc[2][4];
#pragma unroll
    for (int i = 0; i < 2; ++i)
#pragma unroll
        for (int j = 0; j < 4; ++j) acc[i][j] = (f32x4){0.f, 0.f, 0.f, 0.f};

    const int lx = l & 15, lq = l >> 4;
#pragma unroll
    for (int c = 0; c < 2; ++c) {
        const int icb = c * 4 + lq;
#pragma unroll
        for (int tap = 0; tap < 9; ++tap) {
            const int dy = tap / 3, dx = tap % 3;
            const size_t wbase = ((size_t)(g * 9 + tap) * 8 + icb) * 64 + lx;
            bfx8 b0 = wr[wbase];
            bfx8 b1 = wr[wbase + 16];
            bfx8 b2 = wr[wbase + 32];
            bfx8 b3 = wr[wbase + 48];
#pragma unroll
            for (int pg = 0; pg < 2; ++pg) {
                int hy = wv * 2 + pg + dy, hx = lx + dx;
                int hp = hy * 18 + hx;
                const bfx8* ap = (const bfx8*)&lds_in[hp * 64 + (((icb + hx + 2 * hy + 5) & 7) << 3)];
                bfx8 a = *ap;
                acc[pg][0] = __builtin_amdgcn_mfma_f32_16x16x32_bf16(a, b0, acc[pg][0], 0, 0, 0);
                acc[pg][1] = __builtin_amdgcn_mfma_f32_16x16x32_bf16(a, b1, acc[pg][1], 0, 0, 0);
                acc[pg][2] = __builtin_amdgcn_mfma_f32_16x16x32_bf16(a, b2, acc[pg][2], 0, 0, 0);
                acc[pg][3] = __builtin_amdgcn_mfma_f32_16x16x32_bf16(a, b3, acc[pg][3], 0, 0, 0);
            }
        }
    }

#pragma unroll
    for (int pg = 0; pg < 2; ++pg) {
#pragma unroll
        for (int ocg = 0; ocg < 4; ++ocg) {
            f32x4 v = acc[pg][ocg];
            if (!ispath_t1) {
                // YH tile-major: [b][tile][192][256 inner]
                unsigned short* op = yh + ((size_t)(b * 256 + tile) * 192 + g * 64 + ocg * 16 + lx) * 256
                                        + (wv * 2 + pg) * 16 + lq * 4;
                ushort4 s4;
                s4.x = (unsigned short)f2bf(fmaxf(v.x, 0.f));
                s4.y = (unsigned short)f2bf(fmaxf(v.y, 0.f));
                s4.z = (unsigned short)f2bf(fmaxf(v.z, 0.f));
                s4.w = (unsigned short)f2bf(fmaxf(v.w, 0.f));
                *(ushort4*)op = s4;
            } else {
                // T1T tiled-interleaved: [b][tile][256][128 swz]
                int icT = g * 64 + ocg * 16 + lx;
                int g16 = icT >> 3;
                unsigned short* tb = t1t + ((size_t)(b * 256 + tile) * 256) * 128;
                int innerb = (wv * 2 + pg) * 16 + lq * 4;
                float vr[4] = {v.x, v.y, v.z, v.w};
#pragma unroll
                for (int r = 0; r < 4; ++r) {
                    int inn = innerb + r;
                    tb[(size_t)inn * 128 + (((g16 + inn) & 15) << 3) + (icT & 7)] =
                        (unsigned short)f2bf(fmaxf(vr[r], 0.f));
                }
            }
        }
    }
}

// ---------------- 1x1 conv via bf16 MFMA from tiled input (FILT path) ----------------
template <int CIN, int OC, bool RELU>
__global__ __launch_bounds__(256) void k_conv1x1_mfma(const unsigned short* __restrict__ inT,
                                                      const bfx8* __restrict__ wr,
                                                      unsigned short* __restrict__ out) {
    constexpr int KB = CIN / 8;
    constexpr int KC = CIN / 32;
    constexpr int NOCT = OC / 16;
    __shared__ short ldsA[256 * CIN] __attribute__((aligned(16)));
    const int tid = threadIdx.x;
    const int l = tid & 63, wv = tid >> 6;
    const int tile = blockIdx.x, b = blockIdx.y;
    const unsigned short* src = inT + ((size_t)(b * 256 + tile) * 256) * CIN;
    constexpr int ITER = (256 * CIN / 8) / 256;
#pragma unroll
    for (int it = 0; it < ITER; ++it) {
        int cc = it * 256 + tid;
        __builtin_amdgcn_global_load_lds(
            (const __attribute__((address_space(1))) void*)(src + (size_t)cc * 8),
            (__attribute__((address_space(3))) void*)((char*)ldsA + (size_t)(it * 256 + wv * 64) * 16),
            16, 0, 0);
    }
    __syncthreads();

    const int lx = l & 15, lq = l >> 4;
#pragma unroll
    for (int o4 = 0; o4 < NOCT / 4; ++o4) {
        f32x4 acc[4][4];
#pragma unroll
        for (int i = 0; i < 4; ++i)
#pragma unroll
            for (int j = 0; j < 4; ++j) acc[i][j] = (f32x4){0.f, 0.f, 0.f, 0.f};
#pragma unroll
        for (int c = 0; c < KC; ++c) {
            const int icb = c * 4 + lq;
            bfx8 bf[4];
#pragma unroll
            for (int ot = 0; ot < 4; ++ot)
                bf[ot] = wr[(size_t)(((o4 * 4 + ot) * KB + icb) * 16) + lx];
#pragma unroll
            for (int pg = 0; pg < 4; ++pg) {
                int inner = (wv * 4 + pg) * 16 + lx;
                const bfx8* ap = (const bfx8*)&ldsA[inner * CIN + (((icb + inner) & (KB - 1)) << 3)];
                bfx8 a = *ap;
                acc[pg][0] = __builtin_amdgcn_mfma_f32_16x16x32_bf16(a, bf[0], acc[pg][0], 0, 0, 0);
                acc[pg][1] = __builtin_amdgcn_mfma_f32_16x16x32_bf16(a, bf[1], acc[pg][1], 0, 0, 0);
                acc[pg][2] = __builtin_amdgcn_mfma_f32_16x16x32_bf16(a, bf[2], acc[pg][2], 0, 0, 0);
                acc[pg][3] = __builtin_amdgcn_mfma_f32_16x16x32_bf16(a, bf[3], acc[pg][3], 0, 0, 0);
            }
        }
#pragma unroll
        for (int pg = 0; pg < 4; ++pg)
#pragma unroll
            for (int ot = 0; ot < 4; ++ot) {
                int oc = (o4 * 4 + ot) * 16 + lx;
                // tile-major out: [b][tile][oc][inner]
                unsigned short* op = out + ((size_t)(b * 256 + tile) * OC + oc) * 256
                                         + (wv * 4 + pg) * 16 + lq * 4;
                f32x4 v = acc[pg][ot];
                ushort4 s4;
                s4.x = (unsigned short)f2bf(RELU ? fmaxf(v.x, 0.f) : v.x);
                s4.y = (unsigned short)f2bf(RELU ? fmaxf(v.y, 0.f) : v.y);
                s4.z = (unsigned short)f2bf(RELU ? fmaxf(v.z, 0.f) : v.z);
                s4.w = (unsigned short)f2bf(RELU ? fmaxf(v.w, 0.f) : v.w);
                *(ushort4*)op = s4;
            }
    }
}

// ---------------- fused 1x1-qkv + dw3x3 + v-filter + per-tile attention dots ----------------
// outputs: VT [b][tile][256 inner][64 ch] bf16 (v only), praw/praw2 per-tile S partials.
__global__ __launch_bounds__(256) void k_qkv_fused(const unsigned short* __restrict__ llp,
                                                   const bfx8* __restrict__ wrq,
                                                   const float* __restrict__ wdw,
                                                   const unsigned short* __restrict__ filt,
                                                   unsigned short* __restrict__ vt,
                                                   float* __restrict__ praw,
                                                   float* __restrict__ praw2) {
    __shared__ short ldsA[336 * 64] __attribute__((aligned(16)));   // halo/qkv0; 1st 32KB -> kbuf
    __shared__ short qsave[64 * 256] __attribute__((aligned(16)));  // q post-dw; -> sred (f32)
    __shared__ float ssq[2][4][64];
    const int tid = threadIdx.x;
    const int l = tid & 63, wv = tid >> 6;
    const int tile = blockIdx.x, b = blockIdx.y;
    const int x0 = (tile & 15) * 16, y0 = (tile >> 4) * 16;
    const unsigned short* src = llp + (size_t)b * PPLANE;

    // stage 18x18x64 halo: 2592 uint4 chunks
#pragma unroll
    for (int it = 0; it < 10; ++it) {
        int cch = it * 256 + tid;
        unsigned row = (unsigned)cch / 144u, col = (unsigned)cch % 144u;
        const unsigned short* ga = src + (size_t)(y0 + row) * PROW + (size_t)x0 * 64 + (size_t)col * 8;
        __builtin_amdgcn_global_load_lds(
            (const __attribute__((address_space(1))) void*)ga,
            (__attribute__((address_space(3))) void*)((char*)ldsA + (size_t)(it * 256 + wv * 64) * 16),
            16, 0, 0);
    }
    if (tid < 32) {
        int cch = 2560 + tid;
        unsigned row = (unsigned)cch / 144u, col = (unsigned)cch % 144u;
        const unsigned short* ga = src + (size_t)(y0 + row) * PROW + (size_t)x0 * 64 + (size_t)col * 8;
        *(uint4*)((char*)ldsA + (size_t)cch * 16) = *(const uint4*)ga;
    }
    __syncthreads();

    // hoist A-frags for my M-tiles into regs (static indexing)
    const int lx = l & 15, lq = l >> 4;
    bfx8 af[6][2];
#pragma unroll
    for (int m = 0; m < 6; ++m) {
        int mt = wv + 4 * m;
        if (mt < 21) {
            int hp = mt * 16 + lx;
            int hy = hp / 18, hx = hp - hy * 18;
#pragma unroll
            for (int kc = 0; kc < 2; ++kc) {
                int icb = kc * 4 + lq;
                af[m][kc] = *(const bfx8*)&ldsA[hp * 64 + (((icb + hx + 2 * hy + 5) & 7) << 3)];
            }
        }
    }
    __syncthreads();   // all halo reads done before overwrite

    for (int g3 = 0; g3 < 3; ++g3) {
        // B-frags for this 64-oc group (L2-resident weights)
        bfx8 bw[2][4];
#pragma unroll
        for (int kc = 0; kc < 2; ++kc)
#pragma unroll
            for (int nt = 0; nt < 4; ++nt)
                bw[kc][nt] = wrq[(size_t)(((g3 * 4 + nt) * 8) + kc * 4 + lq) * 16 + lx];
        // MFMA + write qkv0 to LDS [hp][64 swz]
#pragma unroll
        for (int m = 0; m < 6; ++m) {
            int mt = wv + 4 * m;
            if (mt < 21) {
                f32x4 acc[4];
#pragma unroll
                for (int nt = 0; nt < 4; ++nt) acc[nt] = (f32x4){0.f, 0.f, 0.f, 0.f};
#pragma unroll
                for (int kc = 0; kc < 2; ++kc) {
                    bfx8 a = af[m][kc];
#pragma unroll
                    for (int nt = 0; nt < 4; ++nt)
                        acc[nt] = __builtin_amdgcn_mfma_f32_16x16x32_bf16(a, bw[kc][nt], acc[nt], 0, 0, 0);
                }
#pragma unroll
                for (int nt = 0; nt < 4; ++nt) {
                    int ocl = nt * 16 + lx;
                    float vr[4] = {acc[nt].x, acc[nt].y, acc[nt].z, acc[nt].w};
#pragma unroll
                    for (int r = 0; r < 4; ++r) {
                        int hp2 = mt * 16 + lq * 4 + r;
                        int hy2 = hp2 / 18, hx2 = hp2 - hy2 * 18;
                        ldsA[hp2 * 64 + ((((ocl >> 3) + hx2 + 2 * hy2) & 7) << 3) + (ocl & 7)] =
                            f2bf(vr[r]);
                    }
                }
            }
        }
        __syncthreads();
        // depthwise 3x3: lane = ch, wave = 4-row segment
        const int ch = l, chg = g3 * 64 + ch;
        float w9[9];
#pragma unroll
        for (int t = 0; t < 9; ++t) w9[t] = wdw[chg * 9 + t];
        float s2 = 0.f;
        u16x8 kpk[4][2];                 // k post-dw (g3==1) held until kbuf write
#pragma unroll
        for (int yy = 0; yy < 4; ++yy) {
            int y = wv * 4 + yy;
            float ln[3][18];
#pragma unroll
            for (int hr = 0; hr < 3; ++hr) {
                int hy = y + hr;
#pragma unroll
                for (int hx = 0; hx < 18; ++hx)
                    ln[hr][hx] = bfu((unsigned short)ldsA[(hy * 18 + hx) * 64 +
                                     ((((ch >> 3) + hx + 2 * hy) & 7) << 3) + (ch & 7)]);
            }
            float ox[16];
#pragma unroll
            for (int xx = 0; xx < 16; ++xx) {
                float s = 0.f;
#pragma unroll
                for (int hr = 0; hr < 3; ++hr)
#pragma unroll
                    for (int dx = 0; dx < 3; ++dx)
                        s = fmaf(ln[hr][xx + dx], w9[hr * 3 + dx], s);
                ox[xx] = s;
            }
            if (g3 == 2) {
                const unsigned short* fp = filt + ((size_t)(b * 256 + tile) * 64 + ch) * 256 + y * 16;
                u16x8 f0 = *(const u16x8*)fp;
                u16x8 f1 = *(const u16x8*)(fp + 8);
#pragma unroll
                for (int k = 0; k < 8; ++k) ox[k]     = fmaf(ox[k],     bfu(f0[k]), ox[k]);
#pragma unroll
                for (int k = 0; k < 8; ++k) ox[8 + k] = fmaf(ox[8 + k], bfu(f1[k]), ox[8 + k]);
                // v -> VT [inner][ch]
                unsigned short* vb = vt + ((size_t)(b * 256 + tile) * 256 + (size_t)y * 16) * 64 + ch;
#pragma unroll
                for (int xx = 0; xx < 16; ++xx) vb[xx * 64] = (unsigned short)f2bf(ox[xx]);
            } else {
#pragma unroll
                for (int xx = 0; xx < 16; ++xx) s2 = fmaf(ox[xx], ox[xx], s2);
                if (g3 == 0) {           // q -> qsave [ch][px swz]
#pragma unroll
                    for (int xx = 0; xx < 16; ++xx) {
                        int px = y * 16 + xx;
                        qsave[ch * 256 + ((((px >> 3) + ch) & 31) << 3) + (px & 7)] =
                            f2bf(ox[xx]);
                    }
                } else {                 // k -> regs (kbuf write deferred past barrier)
#pragma unroll
                    for (int xx = 0; xx < 8; ++xx)  kpk[yy][0][xx] = (unsigned short)f2bf(ox[xx]);
#pragma unroll
                    for (int xx = 0; xx < 8; ++xx)  kpk[yy][1][xx] = (unsigned short)f2bf(ox[8 + xx]);
                }
            }
        }
        if (g3 == 0) ssq[0][wv][ch] = s2;
        if (g3 == 1) {
            ssq[1][wv][ch] = s2;
            __syncthreads();             // all ldsA (qkv0-k) reads done
            // k -> kbuf (aliases ldsA) [ch][px swz]
            short* kbuf = ldsA;
#pragma unroll
            for (int yy = 0; yy < 4; ++yy) {
                int y = wv * 4 + yy;
#pragma unroll
                for (int xx = 0; xx < 16; ++xx) {
                    int px = y * 16 + xx;
                    kbuf[ch * 256 + ((((px >> 3) + ch) & 31) << 3) + (px & 7)] =
                        (short)kpk[yy][xx >> 3][xx & 7];
                }
            }
            __syncthreads();             // kbuf + qsave ready
            // S partial via MFMA: wave wv covers K-chunks 2wv, 2wv+1 (its own 64 px)
            f32x4 sacc[4];
#pragma unroll
            for (int t16 = 0; t16 < 4; ++t16) sacc[t16] = (f32x4){0.f, 0.f, 0.f, 0.f};
#pragma unroll
            for (int kc2 = 0; kc2 < 2; ++kc2) {
                int kc = wv * 2 + kc2;
#pragma unroll
                for (int t16 = 0; t16 < 4; ++t16) {
                    int chh = t16 * 16 + lx;
                    int go = chh * 256 + (((kc * 4 + lq + chh) & 31) << 3);
                    bfx8 aq = *(const bfx8*)&qsave[go];
                    bfx8 bk = *(const bfx8*)&kbuf[go];
                    sacc[t16] = __builtin_amdgcn_mfma_f32_16x16x32_bf16(aq, bk, sacc[t16], 0, 0, 0);
                }
            }
            __syncthreads();             // qsave/kbuf reads done
            float* sred = (float*)qsave; // alias
#pragma unroll
            for (int t16 = 0; t16 < 4; ++t16)
                *(f32x4*)&sred[((wv * 4 + t16) * 64 + l) * 4] = sacc[t16];
            __syncthreads();
            {   // cross-wave reduce -> praw; sumsq -> praw2
                int t16r = tid >> 6, lr = tid & 63;
                f32x4 s0 = *(const f32x4*)&sred[((0 * 4 + t16r) * 64 + lr) * 4];
                f32x4 s1 = *(const f32x4*)&sred[((1 * 4 + t16r) * 64 + lr) * 4];
                f32x4 s2r = *(const f32x4*)&sred[((2 * 4 + t16r) * 64 + lr) * 4];
                f32x4 s3 = *(const f32x4*)&sred[((3 * 4 + t16r) * 64 + lr) * 4];
                f32x4 sum = s0 + s1 + s2r + s3;
                *(f32x4*)&praw[(((size_t)(b * 256 + tile) * 4 + t16r) * 64 + lr) * 4] = sum;
                if (tid < 128) {
                    int which = tid >> 6, chh = tid & 63;
                    praw2[(size_t)(b * 256 + tile) * 128 + tid] =
                        ssq[which][0][chh] + ssq[which][1][chh] +
                        ssq[which][2][chh] + ssq[which][3][chh];
                }
            }
        }
        __syncthreads();
    }
}

// ---------------- merged: scale+l2norm+softmax over tiles, then M_b = W*blockdiag(attn) ----------------
__global__ __launch_bounds__(512) void k_soft_prep(const float* __restrict__ praw,
                                                   const float* __restrict__ praw2,
                                                   const float* __restrict__ temp,
                                                   const float* __restrict__ wproj,
                                                   short* __restrict__ mrep) {
    __shared__ float sm[512];
    __shared__ float ash[512];
    const int b = blockIdx.x, tid = threadIdx.x;   // 512 threads: (hd, t)
    const int hd = tid >> 6, t = tid & 63;
    const int c = t >> 3, d = t & 7;
    const int t16 = hd >> 1, half = hd & 1;
    const int cl = half * 8 + c, dl = half * 8 + d;
    const float* pb = praw + ((size_t)(b * 256) * 4 + t16) * 256 + ((cl >> 2) * 16 + dl) * 4 + (cl & 3);
    const float* p2 = praw2 + (size_t)(b * 256) * 128;
    float s = 0.f, sq = 0.f, sk = 0.f;
    for (int tile = 0; tile < 256; ++tile) {
        s  += pb[(size_t)tile * 1024];
        sq += p2[(size_t)tile * 128 + hd * 8 + c];
        sk += p2[(size_t)tile * 128 + 64 + hd * 8 + d];
    }
    float nq = fmaxf(sqrtf(sq), 1e-12f);
    float nk = fmaxf(sqrtf(sk), 1e-12f);
    s = s / (nq * nk) * temp[hd];
    sm[tid] = s;
    __syncthreads();
    float mx = -1e30f;
#pragma unroll
    for (int dd = 0; dd < 8; ++dd) mx = fmaxf(mx, sm[hd * 64 + c * 8 + dd]);
    float e = __expf(s - mx);
    ash[tid] = e;
    __syncthreads();
    float sum = 0.f;
#pragma unroll
    for (int dd = 0; dd < 8; ++dd) sum += ash[hd * 64 + c * 8 + dd];
    float a = e / sum;
    __syncthreads();
    ash[tid] = a;                         // attn_b[hd][c][d]
    __syncthreads();
    // M_b fragments: 4096 entries, 8 per thread
#pragma unroll
    for (int i = 0; i < 8; ++i) {
        int idx = tid * 8 + i;
        int j = idx & 7, o16 = (idx >> 3) & 15, icb = (idx >> 7) & 7, oct = idx >> 10;
        int oc = oct * 16 + o16;
        float m = 0.f;
#pragma unroll
        for (int c8 = 0; c8 < 8; ++c8)
            m = fmaf(wproj[(size_t)oc * 64 + icb * 8 + c8], ash[icb * 64 + c8 * 8 + j], m);
        mrep[(size_t)b * 4096 + idx] = f2bf(m);
    }
}

// ---------------- fused (W·attn)·v via MFMA + IDWT -> fp32 out ----------------
__global__ __launch_bounds__(256) void k_attnout_idwt(const unsigned short* __restrict__ vt,
                                                      const bfx8* __restrict__ mrep,
                                                      const unsigned short* __restrict__ yht,
                                                      float* __restrict__ out) {
    const int tid = threadIdx.x;
    const int l = tid & 63, wv = tid >> 6;
    const int lx = l & 15, lq = l >> 4;
    const int tile = blockIdx.x, b = blockIdx.y;
    const int x0 = (tile & 15) * 16, y0 = (tile >> 4) * 16;
    const bfx8* vtb = (const bfx8*)(vt + (size_t)(b * 256 + tile) * 256 * 64);
    const bfx8* mb = mrep + (size_t)b * 512;

    bfx8 bw[2][4];
#pragma unroll
    for (int kc = 0; kc < 2; ++kc)
#pragma unroll
        for (int nt = 0; nt < 4; ++nt)
            bw[kc][nt] = mb[(nt * 8 + kc * 4 + lq) * 16 + lx];

    const unsigned short* yb = yht + (size_t)(b * 256 + tile) * 192 * 256;

#pragma unroll
    for (int pg = 0; pg < 4; ++pg) {
        const int mt = wv * 4 + pg;
        const int y = y0 + mt;
        bfx8 a0 = vtb[(mt * 16 + lx) * 8 + lq];
        bfx8 a1 = vtb[(mt * 16 + lx) * 8 + 4 + lq];

        f32x4 acc[4];
#pragma unroll
        for (int nt = 0; nt < 4; ++nt) acc[nt] = (f32x4){0.f, 0.f, 0.f, 0.f};
#pragma unroll
        for (int nt = 0; nt < 4; ++nt) {
            acc[nt] = __builtin_amdgcn_mfma_f32_16x16x32_bf16(a0, bw[0][nt], acc[nt], 0, 0, 0);
            acc[nt] = __builtin_amdgcn_mfma_f32_16x16x32_bf16(a1, bw[1][nt], acc[nt], 0, 0, 0);
        }
#pragma unroll
        for (int nt = 0; nt < 4; ++nt) {
            const int oc = nt * 16 + lx;
            const int inner = mt * 16 + lq * 4;
            const unsigned short* yp = yb + (size_t)oc * 256 + inner;
            u16x4 lh4 = *(const u16x4*)yp;
            u16x4 hl4 = *(const u16x4*)(yp + (size_t)64 * 256);
            u16x4 hh4 = *(const u16x4*)(yp + (size_t)128 * 256);
            float e0[8], e1[8];
#pragma unroll
            for (int r = 0; r < 4; ++r) {
                float s  = acc[nt][r];
                float LH = bfu(lh4[r]), HL = bfu(hl4[r]), HHv = bfu(hh4[r]);
                e0[2 * r]     = (s - LH - HL + HHv) * 0.5f;
                e0[2 * r + 1] = (s - LH + HL - HHv) * 0.5f;
                e1[2 * r]     = (s + LH - HL - HHv) * 0.5f;
                e1[2 * r + 1] = (s + LH + HL + HHv) * 0.5f;
            }
            float* o0 = out + ((size_t)(b * 64 + oc) * HF + 2 * y) * WF + 2 * (x0 + lq * 4);
            *(float4*)o0            = *(float4*)&e0[0];
            *(float4*)(o0 + 4)      = *(float4*)&e0[4];
            *(float4*)(o0 + WF)     = *(float4*)&e1[0];
            *(float4*)(o0 + WF + 4) = *(float4*)&e1[4];
        }
    }
}

extern "C" void kernel_launch(void* const* d_in, const int* in_sizes, int n_in,
                              void* d_out, int out_size, void* d_ws, size_t ws_size,
                              hipStream_t stream) {
    const float* x      = (const float*)d_in[0];
    const float* w_hc1  = (const float*)d_in[1];
    const float* w_hc2  = (const float*)d_in[2];
    const float* w_ho   = (const float*)d_in[3];
    const float* w_qkv  = (const float*)d_in[4];
    const float* w_dw   = (const float*)d_in[5];
    const float* w_proj = (const float*)d_in[6];
    const float* temp   = (const float*)d_in[7];
    float* out = (float*)d_out;

    char* base = (char*)d_ws;
    unsigned short* TILED = (unsigned short*)(base + 0);             // 12 padded planes
    unsigned short* LLP   = (unsigned short*)(base + 102242304ULL);  // 4 padded planes (LL)
    unsigned short* YH    = (unsigned short*)(base + 136323072ULL);  // 96 MiB bf16 tile-major
    unsigned short* T1T   = (unsigned short*)(base + 236986368ULL);  // 64 MiB bf16 tiled [..][128]
    unsigned short* FILT  = (unsigned short*)(base + 304095232ULL);  // 32 MiB bf16 tile-major
    unsigned short* VT    = (unsigned short*)(base + 337649664ULL);  // 32 MiB bf16 v tile-major
    float*          PRAW  = (float*)(base + 371204096ULL);           // 4 MiB per-tile S partials
    float*          PRAW2 = (float*)(base + 375398400ULL);           // 512 KiB sumsq partials
    short* WREP_HO  = (short*)(base + 375922688ULL);
    short* WREP_HC1 = (short*)(base + 376143872ULL);
    short* WREP_HC2 = (short*)(base + 376291328ULL);
    short* WREP_QKV = (short*)(base + 376307712ULL);
    short* MREP     = (short*)(base + 376332288ULL);                 // BN*4096 bf16

    // 0. merged setup: ring-zero 16 planes + all repacks (816 blocks)
    k_setup<<<816, 256, 0, stream>>>(TILED, w_ho, w_hc1, w_hc2, w_qkv,
                                     WREP_HO, WREP_HC1, WREP_HC2, WREP_QKV);
    // 1. DWT -> padded bf16 LH/HL/HH + LL
    k_dwt<<<dim3(512, BN), 256, 0, stream>>>(x, TILED, LLP);
    // 2. merged gconv3x3 (512-thread blocks): yh (3 groups) + t1 (2 groups)
    k_gconv3x3_mfma<<<dim3(256, 5, BN), 512, 0, stream>>>(TILED, (const bfx8*)WREP_HO,
                                                          (const bfx8*)WREP_HC1, YH, T1T);
    // 3. filter_hv = relu(1x1(t1, w_hc2)) -> tile-major bf16
    k_conv1x1_mfma<128, 64, true><<<dim3(256, BN), 256, 0, stream>>>(T1T, (const bfx8*)WREP_HC2, FILT);
    // 4. qkv fused: 1x1 + dw3x3 + v-filter + per-tile attention dots -> VT, PRAW, PRAW2
    k_qkv_fused<<<dim3(256, BN), 256, 0, stream>>>(LLP, (const bfx8*)WREP_QKV, w_dw, FILT,
                                                   VT, PRAW, PRAW2);
    // 5. merged softmax (incl. l2norm) + M_b fragments
    k_soft_prep<<<BN, 512, 0, stream>>>(PRAW, PRAW2, temp, w_proj, MREP);
    // 6. fused (W*attn)*v via MFMA + IDWT -> fp32 out
    k_attnout_idwt<<<dim3(256, BN), 256, 0, stream>>>(VT, (const bfx8*)MREP, YH, out);
}

// Round 17
// 552.008 us; speedup vs baseline: 1.0113x; 1.0113x over previous
//
#include <hip/hip_runtime.h>
#include <hip/hip_bf16.h>

#define BN 4
#define DIM 64
#define NHEADS 8
#define HH 256
#define WH 256
#define NP (HH*WH)      // 65536
#define HF 512
#define WF 512

#define PD 258                       // padded dim
#define PROW (PD*64)                 // shorts per padded row
#define PPLANE ((size_t)PD*PD*64)    // shorts per padded plane

typedef __attribute__((ext_vector_type(8))) short bfx8;           // 8 bf16
typedef __attribute__((ext_vector_type(8))) unsigned short u16x8; // 8 bf16 bits
typedef __attribute__((ext_vector_type(4))) unsigned short u16x4; // 4 bf16 bits
typedef __attribute__((ext_vector_type(4))) float f32x4;          // MFMA C/D frag

static __device__ __forceinline__ short f2bf(float f) {
    unsigned u = __float_as_uint(f);
    unsigned r = (u + 0x7FFFu + ((u >> 16) & 1u)) >> 16;   // RNE
    return (short)r;
}
static __device__ __forceinline__ float bfu(unsigned short u) {
    return __uint_as_float((unsigned)u << 16);
}

// ---------------- merged setup: ring-zero 16 planes + all weight repacks ----------------
__global__ __launch_bounds__(256) void k_setup(unsigned short* __restrict__ tiled16,
                                               const float* __restrict__ w_ho,
                                               const float* __restrict__ w_hc1,
                                               const float* __restrict__ w_hc2,
                                               const float* __restrict__ w_qkv,
                                               short* __restrict__ wrHO,
                                               short* __restrict__ wrHC1,
                                               short* __restrict__ wrHC2,
                                               short* __restrict__ wrQKV) {
    int bx = blockIdx.x, tid = threadIdx.x;
    if (bx < 16) {                        // pad-ring zero, 16 planes (12 TILED + 4 LLP)
        char* base = (char*)(tiled16 + (size_t)bx * PPLANE);
        const int ROWB = PROW * 2;
        for (int k = tid; k < 8224; k += 256) {
            char* dst;
            if (k < 2064) dst = base + (size_t)k * 16;
            else if (k < 4128) dst = base + (size_t)257 * ROWB + (size_t)(k - 2064) * 16;
            else if (k < 6176) { int r = (k - 4128) >> 3, s = (k - 4128) & 7;
                dst = base + (size_t)(r + 1) * ROWB + (size_t)s * 16; }
            else { int r = (k - 6176) >> 3, s = (k - 6176) & 7;
                dst = base + (size_t)(r + 1) * ROWB + 257 * 128 + (size_t)s * 16; }
            *(uint4*)dst = (uint4){0, 0, 0, 0};
        }
        return;
    }
    if (bx < 16 + 432 + 288) {            // 3x3 repacks: OIHW -> [g][tap][icb][oc][8]
        const float* w = (bx < 448) ? w_ho : w_hc1;
        short* wrep = (bx < 448) ? wrHO : wrHC1;
        int t = (bx - ((bx < 448) ? 16 : 448)) * 256 + tid;
        unsigned g   = (unsigned)t / 36864u;
        unsigned r1  = (unsigned)t % 36864u;
        unsigned tap = r1 / 4096u;
        unsigned r2  = r1 % 4096u;
        unsigned icb = r2 / 512u;
        unsigned r3  = r2 % 512u;
        unsigned oc  = r3 >> 3;
        unsigned j   = r3 & 7u;
        wrep[t] = f2bf(w[(((size_t)g * 64 + oc) * 64 + icb * 8u + j) * 9 + tap]);
        return;
    }
    if (bx < 16 + 432 + 288 + 32) {       // w_hc2 [64][128] -> [oct][icb][oc16][8]
        int t = (bx - 736) * 256 + tid;
        int j = t & 7, gr = t >> 3, o16 = gr & 15, X = gr >> 4;
        int icb = X % 16, oct = X / 16;
        wrHC2[t] = f2bf(w_hc2[(size_t)(oct * 16 + o16) * 128 + icb * 8 + j]);
        return;
    }
    {                                     // w_qkv [192][64] -> [oct][icb][oc16][8]
        int t = (bx - 768) * 256 + tid;
        int j = t & 7, gr = t >> 3, o16 = gr & 15, X = gr >> 4;
        int icb = X % 8, oct = X / 8;
        wrQKV[t] = f2bf(w_qkv[(size_t)(oct * 16 + o16) * 64 + icb * 8 + j]);
    }
}

// ---------------- DWT -> 4 padded-swizzled bf16 planes (LH/HL/HH in TILED, LL in LLP) ----------------
__global__ __launch_bounds__(256) void k_dwt(const float* __restrict__ x,
                                             unsigned short* __restrict__ tiled,
                                             unsigned short* __restrict__ llp) {
    __shared__ unsigned short lds[3 * 128 * 64] __attribute__((aligned(16)));
    const int tid = threadIdx.x;
    const int pid = blockIdx.x;              // 512 = 32 y-patches x 16 x-patches
    const int b = blockIdx.y;
    const int y0 = (pid >> 4) * 8, x0 = (pid & 15) * 16;
    const int quad = tid & 127;
    const int qy = quad >> 4, qx = quad & 15;
    const int gy = y0 + qy, gx = x0 + qx;
    const int ich = tid >> 7;                // 0/1
    unsigned short* llb = llp + (size_t)b * PPLANE + ((size_t)(gy + 1) * PD + (gx + 1)) * 64;

#pragma unroll 4
    for (int it = 0; it < 16; ++it) {
        int ic = it * 4 + ich * 2;           // handle ic, ic+1 (pair => b32 writes)
        unsigned g = (((unsigned)(ic >> 3)) + (unsigned)gx + 2u * (unsigned)gy) & 7u;
        unsigned swz = (unsigned)quad * 64 + (g << 3) + (unsigned)(ic & 7);
        unsigned pk[3], pll;
#pragma unroll
        for (int s = 0; s < 2; ++s) {
            const float* px = x + (((size_t)(b * 64 + ic + s) * HF) + 2 * gy) * WF + 2 * gx;
            float2 e0 = *(const float2*)px;
            float2 e1 = *(const float2*)(px + WF);
            float a = e0.x, bb = e0.y, c = e1.x, d = e1.y;
            unsigned ll = (unsigned short)f2bf(( a + bb + c + d) * 0.5f);
            unsigned lh = (unsigned short)f2bf((-a - bb + c + d) * 0.5f);
            unsigned hl = (unsigned short)f2bf((-a + bb - c + d) * 0.5f);
            unsigned hh = (unsigned short)f2bf(( a - bb - c + d) * 0.5f);
            if (s == 0) { pll = ll; pk[0] = lh; pk[1] = hl; pk[2] = hh; }
            else { pll |= ll << 16; pk[0] |= lh << 16; pk[1] |= hl << 16; pk[2] |= hh << 16; }
        }
        *(unsigned*)&lds[swz]          = pk[0];
        *(unsigned*)&lds[8192 + swz]   = pk[1];
        *(unsigned*)&lds[16384 + swz]  = pk[2];
        *(unsigned*)&llb[(g << 3) + (unsigned)(ic & 7)] = pll;
    }
    __syncthreads();
#pragma unroll
    for (int it = 0; it < 12; ++it) {
        int cch = tid + it * 256;            // 0..3071 (uint4 chunks)
        int p = cch >> 10, rem = cch & 1023;
        int row = rem >> 7, col = rem & 127;
        unsigned short* dst = tiled + ((size_t)(b * 3 + p) * PD + (y0 + row + 1)) * PROW
                                    + (size_t)(x0 + 1) * 64 + (size_t)col * 8;
        *(uint4*)dst = *(const uint4*)((const char*)lds + (size_t)cch * 16);
    }
}

// ---------------- merged grouped 3x3 convs (yh: g5=0..2 -> YH; t1: g5=3..4 -> T1T) ----------------
__global__ __launch_bounds__(256) void k_gconv3x3_mfma(const unsigned short* __restrict__ tiled,
                                                       const bfx8* __restrict__ wrHO,
                                                       const bfx8* __restrict__ wrHC1,
                                                       unsigned short* __restrict__ yh,
                                                       unsigned short* __restrict__ t1t) {
    __shared__ short lds_in[324 * 64] __attribute__((aligned(16)));
    const int tid = threadIdx.x;
    const int l = tid & 63, wv = tid >> 6;
    const int tile = blockIdx.x;
    const int x0 = (tile & 15) * 16, y0 = (tile >> 4) * 16;
    const int g5 = blockIdx.y, b = blockIdx.z;
    const bool ispath_t1 = (g5 >= 3);
    const int g = ispath_t1 ? (g5 - 3) : g5;            // source plane index
    const bfx8* wr = ispath_t1 ? wrHC1 : wrHO;
    const unsigned short* src = tiled + (size_t)(b * 3 + g) * PPLANE;

#pragma unroll
    for (int it = 0; it < 10; ++it) {
        int cch = it * 256 + tid;
        unsigned row = (unsigned)cch / 144u, col = (unsigned)cch % 144u;
        const unsigned short* ga = src + (size_t)(y0 + row) * PROW + (size_t)x0 * 64 + (size_t)col * 8;
        __builtin_amdgcn_global_load_lds(
            (const __attribute__((address_space(1))) void*)ga,
            (__attribute__((address_space(3))) void*)((char*)lds_in + (size_t)(it * 256 + wv * 64) * 16),
            16, 0, 0);
    }
    if (tid < 32) {
        int cch = 2560 + tid;
        unsigned row = (unsigned)cch / 144u, col = (unsigned)cch % 144u;
        const unsigned short* ga = src + (size_t)(y0 + row) * PROW + (size_t)x0 * 64 + (size_t)col * 8;
        *(uint4*)((char*)lds_in + (size_t)cch * 16) = *(const uint4*)ga;
    }
    __syncthreads();

    f32x4 acc[4][4];
#pragma unroll
    for (int i = 0; i < 4; ++i)
#pragma unroll
        for (int j = 0; j < 4; ++j) acc[i][j] = (f32x4){0.f, 0.f, 0.f, 0.f};

    const int lx = l & 15, lq = l >> 4;
#pragma unroll
    for (int c = 0; c < 2; ++c) {
        const int icb = c * 4 + lq;
#pragma unroll
        for (int tap = 0; tap < 9; ++tap) {
            const int dy = tap / 3, dx = tap % 3;
            const size_t wbase = ((size_t)(g * 9 + tap) * 8 + icb) * 64 + lx;
            bfx8 b0 = wr[wbase];
            bfx8 b1 = wr[wbase + 16];
            bfx8 b2 = wr[wbase + 32];
            bfx8 b3 = wr[wbase + 48];
#pragma unroll
            for (int pg = 0; pg < 4; ++pg) {
                int hy = wv * 4 + pg + dy, hx = lx + dx;
                int hp = hy * 18 + hx;
                const bfx8* ap = (const bfx8*)&lds_in[hp * 64 + (((icb + hx + 2 * hy + 5) & 7) << 3)];
                bfx8 a = *ap;
                acc[pg][0] = __builtin_amdgcn_mfma_f32_16x16x32_bf16(a, b0, acc[pg][0], 0, 0, 0);
                acc[pg][1] = __builtin_amdgcn_mfma_f32_16x16x32_bf16(a, b1, acc[pg][1], 0, 0, 0);
                acc[pg][2] = __builtin_amdgcn_mfma_f32_16x16x32_bf16(a, b2, acc[pg][2], 0, 0, 0);
                acc[pg][3] = __builtin_amdgcn_mfma_f32_16x16x32_bf16(a, b3, acc[pg][3], 0, 0, 0);
            }
        }
    }

#pragma unroll
    for (int pg = 0; pg < 4; ++pg) {
#pragma unroll
        for (int ocg = 0; ocg < 4; ++ocg) {
            f32x4 v = acc[pg][ocg];
            if (!ispath_t1) {
                // YH tile-major: [b][tile][192][256 inner]
                unsigned short* op = yh + ((size_t)(b * 256 + tile) * 192 + g * 64 + ocg * 16 + lx) * 256
                                        + (wv * 4 + pg) * 16 + lq * 4;
                ushort4 s4;
                s4.x = (unsigned short)f2bf(fmaxf(v.x, 0.f));
                s4.y = (unsigned short)f2bf(fmaxf(v.y, 0.f));
                s4.z = (unsigned short)f2bf(fmaxf(v.z, 0.f));
                s4.w = (unsigned short)f2bf(fmaxf(v.w, 0.f));
                *(ushort4*)op = s4;
            } else {
                // T1T tiled-interleaved: [b][tile][256][128 swz]
                int icT = g * 64 + ocg * 16 + lx;
                int g16 = icT >> 3;
                unsigned short* tb = t1t + ((size_t)(b * 256 + tile) * 256) * 128;
                int innerb = (wv * 4 + pg) * 16 + lq * 4;
                float vr[4] = {v.x, v.y, v.z, v.w};
#pragma unroll
                for (int r = 0; r < 4; ++r) {
                    int inn = innerb + r;
                    tb[(size_t)inn * 128 + (((g16 + inn) & 15) << 3) + (icT & 7)] =
                        (unsigned short)f2bf(fmaxf(vr[r], 0.f));
                }
            }
        }
    }
}

// ---------------- 1x1 conv via bf16 MFMA from tiled input (FILT path) ----------------
template <int CIN, int OC, bool RELU>
__global__ __launch_bounds__(256) void k_conv1x1_mfma(const unsigned short* __restrict__ inT,
                                                      const bfx8* __restrict__ wr,
                                                      unsigned short* __restrict__ out) {
    constexpr int KB = CIN / 8;
    constexpr int KC = CIN / 32;
    constexpr int NOCT = OC / 16;
    __shared__ short ldsA[256 * CIN] __attribute__((aligned(16)));
    const int tid = threadIdx.x;
    const int l = tid & 63, wv = tid >> 6;
    const int tile = blockIdx.x, b = blockIdx.y;
    const unsigned short* src = inT + ((size_t)(b * 256 + tile) * 256) * CIN;
    constexpr int ITER = (256 * CIN / 8) / 256;
#pragma unroll
    for (int it = 0; it < ITER; ++it) {
        int cc = it * 256 + tid;
        __builtin_amdgcn_global_load_lds(
            (const __attribute__((address_space(1))) void*)(src + (size_t)cc * 8),
            (__attribute__((address_space(3))) void*)((char*)ldsA + (size_t)(it * 256 + wv * 64) * 16),
            16, 0, 0);
    }
    __syncthreads();

    const int lx = l & 15, lq = l >> 4;
#pragma unroll
    for (int o4 = 0; o4 < NOCT / 4; ++o4) {
        f32x4 acc[4][4];
#pragma unroll
        for (int i = 0; i < 4; ++i)
#pragma unroll
            for (int j = 0; j < 4; ++j) acc[i][j] = (f32x4){0.f, 0.f, 0.f, 0.f};
#pragma unroll
        for (int c = 0; c < KC; ++c) {
            const int icb = c * 4 + lq;
            bfx8 bf[4];
#pragma unroll
            for (int ot = 0; ot < 4; ++ot)
                bf[ot] = wr[(size_t)(((o4 * 4 + ot) * KB + icb) * 16) + lx];
#pragma unroll
            for (int pg = 0; pg < 4; ++pg) {
                int inner = (wv * 4 + pg) * 16 + lx;
                const bfx8* ap = (const bfx8*)&ldsA[inner * CIN + (((icb + inner) & (KB - 1)) << 3)];
                bfx8 a = *ap;
                acc[pg][0] = __builtin_amdgcn_mfma_f32_16x16x32_bf16(a, bf[0], acc[pg][0], 0, 0, 0);
                acc[pg][1] = __builtin_amdgcn_mfma_f32_16x16x32_bf16(a, bf[1], acc[pg][1], 0, 0, 0);
                acc[pg][2] = __builtin_amdgcn_mfma_f32_16x16x32_bf16(a, bf[2], acc[pg][2], 0, 0, 0);
                acc[pg][3] = __builtin_amdgcn_mfma_f32_16x16x32_bf16(a, bf[3], acc[pg][3], 0, 0, 0);
            }
        }
#pragma unroll
        for (int pg = 0; pg < 4; ++pg)
#pragma unroll
            for (int ot = 0; ot < 4; ++ot) {
                int oc = (o4 * 4 + ot) * 16 + lx;
                // tile-major out: [b][tile][oc][inner]
                unsigned short* op = out + ((size_t)(b * 256 + tile) * OC + oc) * 256
                                         + (wv * 4 + pg) * 16 + lq * 4;
                f32x4 v = acc[pg][ot];
                ushort4 s4;
                s4.x = (unsigned short)f2bf(RELU ? fmaxf(v.x, 0.f) : v.x);
                s4.y = (unsigned short)f2bf(RELU ? fmaxf(v.y, 0.f) : v.y);
                s4.z = (unsigned short)f2bf(RELU ? fmaxf(v.z, 0.f) : v.z);
                s4.w = (unsigned short)f2bf(RELU ? fmaxf(v.w, 0.f) : v.w);
                *(ushort4*)op = s4;
            }
    }
}

// ---------------- fused 1x1-qkv + dw3x3 + v-filter + per-tile attention dots ----------------
// outputs: VT [b][tile][256 inner][64 ch] bf16 (v only), praw/praw2 per-tile S partials.
__global__ __launch_bounds__(256) void k_qkv_fused(const unsigned short* __restrict__ llp,
                                                   const bfx8* __restrict__ wrq,
                                                   const float* __restrict__ wdw,
                                                   const unsigned short* __restrict__ filt,
                                                   unsigned short* __restrict__ vt,
                                                   float* __restrict__ praw,
                                                   float* __restrict__ praw2) {
    __shared__ short ldsA[336 * 64] __attribute__((aligned(16)));   // halo/qkv0; 1st 32KB -> kbuf
    __shared__ short qsave[64 * 256] __attribute__((aligned(16)));  // q post-dw; -> sred (f32)
    __shared__ float ssq[2][4][64];
    const int tid = threadIdx.x;
    const int l = tid & 63, wv = tid >> 6;
    const int tile = blockIdx.x, b = blockIdx.y;
    const int x0 = (tile & 15) * 16, y0 = (tile >> 4) * 16;
    const unsigned short* src = llp + (size_t)b * PPLANE;

    // stage 18x18x64 halo: 2592 uint4 chunks
#pragma unroll
    for (int it = 0; it < 10; ++it) {
        int cch = it * 256 + tid;
        unsigned row = (unsigned)cch / 144u, col = (unsigned)cch % 144u;
        const unsigned short* ga = src + (size_t)(y0 + row) * PROW + (size_t)x0 * 64 + (size_t)col * 8;
        __builtin_amdgcn_global_load_lds(
            (const __attribute__((address_space(1))) void*)ga,
            (__attribute__((address_space(3))) void*)((char*)ldsA + (size_t)(it * 256 + wv * 64) * 16),
            16, 0, 0);
    }
    if (tid < 32) {
        int cch = 2560 + tid;
        unsigned row = (unsigned)cch / 144u, col = (unsigned)cch % 144u;
        const unsigned short* ga = src + (size_t)(y0 + row) * PROW + (size_t)x0 * 64 + (size_t)col * 8;
        *(uint4*)((char*)ldsA + (size_t)cch * 16) = *(const uint4*)ga;
    }
    __syncthreads();

    // hoist A-frags for my M-tiles into regs (static indexing)
    const int lx = l & 15, lq = l >> 4;
    bfx8 af[6][2];
#pragma unroll
    for (int m = 0; m < 6; ++m) {
        int mt = wv + 4 * m;
        if (mt < 21) {
            int hp = mt * 16 + lx;
            int hy = hp / 18, hx = hp - hy * 18;
#pragma unroll
            for (int kc = 0; kc < 2; ++kc) {
                int icb = kc * 4 + lq;
                af[m][kc] = *(const bfx8*)&ldsA[hp * 64 + (((icb + hx + 2 * hy + 5) & 7) << 3)];
            }
        }
    }
    __syncthreads();   // all halo reads done before overwrite

    for (int g3 = 0; g3 < 3; ++g3) {
        // B-frags for this 64-oc group (L2-resident weights)
        bfx8 bw[2][4];
#pragma unroll
        for (int kc = 0; kc < 2; ++kc)
#pragma unroll
            for (int nt = 0; nt < 4; ++nt)
                bw[kc][nt] = wrq[(size_t)(((g3 * 4 + nt) * 8) + kc * 4 + lq) * 16 + lx];
        // MFMA + write qkv0 to LDS [hp][64 swz]
#pragma unroll
        for (int m = 0; m < 6; ++m) {
            int mt = wv + 4 * m;
            if (mt < 21) {
                f32x4 acc[4];
#pragma unroll
                for (int nt = 0; nt < 4; ++nt) acc[nt] = (f32x4){0.f, 0.f, 0.f, 0.f};
#pragma unroll
                for (int kc = 0; kc < 2; ++kc) {
                    bfx8 a = af[m][kc];
#pragma unroll
                    for (int nt = 0; nt < 4; ++nt)
                        acc[nt] = __builtin_amdgcn_mfma_f32_16x16x32_bf16(a, bw[kc][nt], acc[nt], 0, 0, 0);
                }
#pragma unroll
                for (int nt = 0; nt < 4; ++nt) {
                    int ocl = nt * 16 + lx;
                    float vr[4] = {acc[nt].x, acc[nt].y, acc[nt].z, acc[nt].w};
#pragma unroll
                    for (int r = 0; r < 4; ++r) {
                        int hp2 = mt * 16 + lq * 4 + r;
                        int hy2 = hp2 / 18, hx2 = hp2 - hy2 * 18;
                        ldsA[hp2 * 64 + ((((ocl >> 3) + hx2 + 2 * hy2) & 7) << 3) + (ocl & 7)] =
                            f2bf(vr[r]);
                    }
                }
            }
        }
        __syncthreads();
        // depthwise 3x3: lane = ch, wave = 4-row segment
        const int ch = l, chg = g3 * 64 + ch;
        float w9[9];
#pragma unroll
        for (int t = 0; t < 9; ++t) w9[t] = wdw[chg * 9 + t];
        float s2 = 0.f;
        u16x8 kpk[4][2];                 // k post-dw (g3==1) held until kbuf write
#pragma unroll
        for (int yy = 0; yy < 4; ++yy) {
            int y = wv * 4 + yy;
            float ln[3][18];
#pragma unroll
            for (int hr = 0; hr < 3; ++hr) {
                int hy = y + hr;
#pragma unroll
                for (int hx = 0; hx < 18; ++hx)
                    ln[hr][hx] = bfu((unsigned short)ldsA[(hy * 18 + hx) * 64 +
                                     ((((ch >> 3) + hx + 2 * hy) & 7) << 3) + (ch & 7)]);
            }
            float ox[16];
#pragma unroll
            for (int xx = 0; xx < 16; ++xx) {
                float s = 0.f;
#pragma unroll
                for (int hr = 0; hr < 3; ++hr)
#pragma unroll
                    for (int dx = 0; dx < 3; ++dx)
                        s = fmaf(ln[hr][xx + dx], w9[hr * 3 + dx], s);
                ox[xx] = s;
            }
            if (g3 == 2) {
                const unsigned short* fp = filt + ((size_t)(b * 256 + tile) * 64 + ch) * 256 + y * 16;
                u16x8 f0 = *(const u16x8*)fp;
                u16x8 f1 = *(const u16x8*)(fp + 8);
#pragma unroll
                for (int k = 0; k < 8; ++k) ox[k]     = fmaf(ox[k],     bfu(f0[k]), ox[k]);
#pragma unroll
                for (int k = 0; k < 8; ++k) ox[8 + k] = fmaf(ox[8 + k], bfu(f1[k]), ox[8 + k]);
                // v -> VT [inner][ch]
                unsigned short* vb = vt + ((size_t)(b * 256 + tile) * 256 + (size_t)y * 16) * 64 + ch;
#pragma unroll
                for (int xx = 0; xx < 16; ++xx) vb[xx * 64] = (unsigned short)f2bf(ox[xx]);
            } else {
#pragma unroll
                for (int xx = 0; xx < 16; ++xx) s2 = fmaf(ox[xx], ox[xx], s2);
                if (g3 == 0) {           // q -> qsave [ch][px swz]
#pragma unroll
                    for (int xx = 0; xx < 16; ++xx) {
                        int px = y * 16 + xx;
                        qsave[ch * 256 + ((((px >> 3) + ch) & 31) << 3) + (px & 7)] =
                            f2bf(ox[xx]);
                    }
                } else {                 // k -> regs (kbuf write deferred past barrier)
#pragma unroll
                    for (int xx = 0; xx < 8; ++xx)  kpk[yy][0][xx] = (unsigned short)f2bf(ox[xx]);
#pragma unroll
                    for (int xx = 0; xx < 8; ++xx)  kpk[yy][1][xx] = (unsigned short)f2bf(ox[8 + xx]);
                }
            }
        }
        if (g3 == 0) ssq[0][wv][ch] = s2;
        if (g3 == 1) {
            ssq[1][wv][ch] = s2;
            __syncthreads();             // all ldsA (qkv0-k) reads done
            // k -> kbuf (aliases ldsA) [ch][px swz]
            short* kbuf = ldsA;
#pragma unroll
            for (int yy = 0; yy < 4; ++yy) {
                int y = wv * 4 + yy;
#pragma unroll
                for (int xx = 0; xx < 16; ++xx) {
                    int px = y * 16 + xx;
                    kbuf[ch * 256 + ((((px >> 3) + ch) & 31) << 3) + (px & 7)] =
                        (short)kpk[yy][xx >> 3][xx & 7];
                }
            }
            __syncthreads();             // kbuf + qsave ready
            // S partial via MFMA: wave wv covers K-chunks 2wv, 2wv+1 (its own 64 px)
            f32x4 sacc[4];
#pragma unroll
            for (int t16 = 0; t16 < 4; ++t16) sacc[t16] = (f32x4){0.f, 0.f, 0.f, 0.f};
#pragma unroll
            for (int kc2 = 0; kc2 < 2; ++kc2) {
                int kc = wv * 2 + kc2;
#pragma unroll
                for (int t16 = 0; t16 < 4; ++t16) {
                    int chh = t16 * 16 + lx;
                    int go = chh * 256 + (((kc * 4 + lq + chh) & 31) << 3);
                    bfx8 aq = *(const bfx8*)&qsave[go];
                    bfx8 bk = *(const bfx8*)&kbuf[go];
                    sacc[t16] = __builtin_amdgcn_mfma_f32_16x16x32_bf16(aq, bk, sacc[t16], 0, 0, 0);
                }
            }
            __syncthreads();             // qsave/kbuf reads done
            float* sred = (float*)qsave; // alias
#pragma unroll
            for (int t16 = 0; t16 < 4; ++t16)
                *(f32x4*)&sred[((wv * 4 + t16) * 64 + l) * 4] = sacc[t16];
            __syncthreads();
            {   // cross-wave reduce -> praw; sumsq -> praw2
                int t16r = tid >> 6, lr = tid & 63;
                f32x4 s0 = *(const f32x4*)&sred[((0 * 4 + t16r) * 64 + lr) * 4];
                f32x4 s1 = *(const f32x4*)&sred[((1 * 4 + t16r) * 64 + lr) * 4];
                f32x4 s2r = *(const f32x4*)&sred[((2 * 4 + t16r) * 64 + lr) * 4];
                f32x4 s3 = *(const f32x4*)&sred[((3 * 4 + t16r) * 64 + lr) * 4];
                f32x4 sum = s0 + s1 + s2r + s3;
                *(f32x4*)&praw[(((size_t)(b * 256 + tile) * 4 + t16r) * 64 + lr) * 4] = sum;
                if (tid < 128) {
                    int which = tid >> 6, chh = tid & 63;
                    praw2[(size_t)(b * 256 + tile) * 128 + tid] =
                        ssq[which][0][chh] + ssq[which][1][chh] +
                        ssq[which][2][chh] + ssq[which][3][chh];
                }
            }
        }
        __syncthreads();
    }
}

// ---------------- merged: scale+l2norm+softmax over tiles, then M_b = W*blockdiag(attn) ----------------
__global__ __launch_bounds__(512) void k_soft_prep(const float* __restrict__ praw,
                                                   const float* __restrict__ praw2,
                                                   const float* __restrict__ temp,
                                                   const float* __restrict__ wproj,
                                                   short* __restrict__ mrep) {
    __shared__ float sm[512];
    __shared__ float ash[512];
    const int b = blockIdx.x, tid = threadIdx.x;   // 512 threads: (hd, t)
    const int hd = tid >> 6, t = tid & 63;
    const int c = t >> 3, d = t & 7;
    const int t16 = hd >> 1, half = hd & 1;
    const int cl = half * 8 + c, dl = half * 8 + d;
    const float* pb = praw + ((size_t)(b * 256) * 4 + t16) * 256 + ((cl >> 2) * 16 + dl) * 4 + (cl & 3);
    const float* p2 = praw2 + (size_t)(b * 256) * 128;
    float s = 0.f, sq = 0.f, sk = 0.f;
    for (int tile = 0; tile < 256; ++tile) {
        s  += pb[(size_t)tile * 1024];
        sq += p2[(size_t)tile * 128 + hd * 8 + c];
        sk += p2[(size_t)tile * 128 + 64 + hd * 8 + d];
    }
    float nq = fmaxf(sqrtf(sq), 1e-12f);
    float nk = fmaxf(sqrtf(sk), 1e-12f);
    s = s / (nq * nk) * temp[hd];
    sm[tid] = s;
    __syncthreads();
    float mx = -1e30f;
#pragma unroll
    for (int dd = 0; dd < 8; ++dd) mx = fmaxf(mx, sm[hd * 64 + c * 8 + dd]);
    float e = __expf(s - mx);
    ash[tid] = e;
    __syncthreads();
    float sum = 0.f;
#pragma unroll
    for (int dd = 0; dd < 8; ++dd) sum += ash[hd * 64 + c * 8 + dd];
    float a = e / sum;
    __syncthreads();
    ash[tid] = a;                         // attn_b[hd][c][d]
    __syncthreads();
    // M_b fragments: 4096 entries, 8 per thread
#pragma unroll
    for (int i = 0; i < 8; ++i) {
        int idx = tid * 8 + i;
        int j = idx & 7, o16 = (idx >> 3) & 15, icb = (idx >> 7) & 7, oct = idx >> 10;
        int oc = oct * 16 + o16;
        float m = 0.f;
#pragma unroll
        for (int c8 = 0; c8 < 8; ++c8)
            m = fmaf(wproj[(size_t)oc * 64 + icb * 8 + c8], ash[icb * 64 + c8 * 8 + j], m);
        mrep[(size_t)b * 4096 + idx] = f2bf(m);
    }
}

// ---------------- fused (W·attn)·v via MFMA + IDWT -> fp32 out ----------------
__global__ __launch_bounds__(256) void k_attnout_idwt(const unsigned short* __restrict__ vt,
                                                      const bfx8* __restrict__ mrep,
                                                      const unsigned short* __restrict__ yht,
                                                      float* __restrict__ out) {
    const int tid = threadIdx.x;
    const int l = tid & 63, wv = tid >> 6;
    const int lx = l & 15, lq = l >> 4;
    const int tile = blockIdx.x, b = blockIdx.y;
    const int x0 = (tile & 15) * 16, y0 = (tile >> 4) * 16;
    const bfx8* vtb = (const bfx8*)(vt + (size_t)(b * 256 + tile) * 256 * 64);
    const bfx8* mb = mrep + (size_t)b * 512;

    bfx8 bw[2][4];
#pragma unroll
    for (int kc = 0; kc < 2; ++kc)
#pragma unroll
        for (int nt = 0; nt < 4; ++nt)
            bw[kc][nt] = mb[(nt * 8 + kc * 4 + lq) * 16 + lx];

    const unsigned short* yb = yht + (size_t)(b * 256 + tile) * 192 * 256;

#pragma unroll
    for (int pg = 0; pg < 4; ++pg) {
        const int mt = wv * 4 + pg;
        const int y = y0 + mt;
        bfx8 a0 = vtb[(mt * 16 + lx) * 8 + lq];
        bfx8 a1 = vtb[(mt * 16 + lx) * 8 + 4 + lq];

        f32x4 acc[4];
#pragma unroll
        for (int nt = 0; nt < 4; ++nt) acc[nt] = (f32x4){0.f, 0.f, 0.f, 0.f};
#pragma unroll
        for (int nt = 0; nt < 4; ++nt) {
            acc[nt] = __builtin_amdgcn_mfma_f32_16x16x32_bf16(a0, bw[0][nt], acc[nt], 0, 0, 0);
            acc[nt] = __builtin_amdgcn_mfma_f32_16x16x32_bf16(a1, bw[1][nt], acc[nt], 0, 0, 0);
        }
#pragma unroll
        for (int nt = 0; nt < 4; ++nt) {
            const int oc = nt * 16 + lx;
            const int inner = mt * 16 + lq * 4;
            const unsigned short* yp = yb + (size_t)oc * 256 + inner;
            u16x4 lh4 = *(const u16x4*)yp;
            u16x4 hl4 = *(const u16x4*)(yp + (size_t)64 * 256);
            u16x4 hh4 = *(const u16x4*)(yp + (size_t)128 * 256);
            float e0[8], e1[8];
#pragma unroll
            for (int r = 0; r < 4; ++r) {
                float s  = acc[nt][r];
                float LH = bfu(lh4[r]), HL = bfu(hl4[r]), HHv = bfu(hh4[r]);
                e0[2 * r]     = (s - LH - HL + HHv) * 0.5f;
                e0[2 * r + 1] = (s - LH + HL - HHv) * 0.5f;
                e1[2 * r]     = (s + LH - HL - HHv) * 0.5f;
                e1[2 * r + 1] = (s + LH + HL + HHv) * 0.5f;
            }
            float* o0 = out + ((size_t)(b * 64 + oc) * HF + 2 * y) * WF + 2 * (x0 + lq * 4);
            *(float4*)o0            = *(float4*)&e0[0];
            *(float4*)(o0 + 4)      = *(float4*)&e0[4];
            *(float4*)(o0 + WF)     = *(float4*)&e1[0];
            *(float4*)(o0 + WF + 4) = *(float4*)&e1[4];
        }
    }
}

extern "C" void kernel_launch(void* const* d_in, const int* in_sizes, int n_in,
                              void* d_out, int out_size, void* d_ws, size_t ws_size,
                              hipStream_t stream) {
    const float* x      = (const float*)d_in[0];
    const float* w_hc1  = (const float*)d_in[1];
    const float* w_hc2  = (const float*)d_in[2];
    const float* w_ho   = (const float*)d_in[3];
    const float* w_qkv  = (const float*)d_in[4];
    const float* w_dw   = (const float*)d_in[5];
    const float* w_proj = (const float*)d_in[6];
    const float* temp   = (const float*)d_in[7];
    float* out = (float*)d_out;

    char* base = (char*)d_ws;
    unsigned short* TILED = (unsigned short*)(base + 0);             // 12 padded planes
    unsigned short* LLP   = (unsigned short*)(base + 102242304ULL);  // 4 padded planes (LL)
    unsigned short* YH    = (unsigned short*)(base + 136323072ULL);  // 96 MiB bf16 tile-major
    unsigned short* T1T   = (unsigned short*)(base + 236986368ULL);  // 64 MiB bf16 tiled [..][128]
    unsigned short* FILT  = (unsigned short*)(base + 304095232ULL);  // 32 MiB bf16 tile-major
    unsigned short* VT    = (unsigned short*)(base + 337649664ULL);  // 32 MiB bf16 v tile-major
    float*          PRAW  = (float*)(base + 371204096ULL);           // 4 MiB per-tile S partials
    float*          PRAW2 = (float*)(base + 375398400ULL);           // 512 KiB sumsq partials
    short* WREP_HO  = (short*)(base + 375922688ULL);
    short* WREP_HC1 = (short*)(base + 376143872ULL);
    short* WREP_HC2 = (short*)(base + 376291328ULL);
    short* WREP_QKV = (short*)(base + 376307712ULL);
    short* MREP     = (short*)(base + 376332288ULL);                 // BN*4096 bf16

    // 0. merged setup: ring-zero 16 planes + all repacks (816 blocks)
    k_setup<<<816, 256, 0, stream>>>(TILED, w_ho, w_hc1, w_hc2, w_qkv,
                                     WREP_HO, WREP_HC1, WREP_HC2, WREP_QKV);
    // 1. DWT -> padded bf16 LH/HL/HH + LL
    k_dwt<<<dim3(512, BN), 256, 0, stream>>>(x, TILED, LLP);
    // 2. merged gconv3x3: yh (3 groups) + t1 (2 groups) in one dispatch
    k_gconv3x3_mfma<<<dim3(256, 5, BN), 256, 0, stream>>>(TILED, (const bfx8*)WREP_HO,
                                                          (const bfx8*)WREP_HC1, YH, T1T);
    // 3. filter_hv = relu(1x1(t1, w_hc2)) -> tile-major bf16
    k_conv1x1_mfma<128, 64, true><<<dim3(256, BN), 256, 0, stream>>>(T1T, (const bfx8*)WREP_HC2, FILT);
    // 4. qkv fused: 1x1 + dw3x3 + v-filter + per-tile attention dots -> VT, PRAW, PRAW2
    k_qkv_fused<<<dim3(256, BN), 256, 0, stream>>>(LLP, (const bfx8*)WREP_QKV, w_dw, FILT,
                                                   VT, PRAW, PRAW2);
    // 5. merged softmax (incl. l2norm) + M_b fragments
    k_soft_prep<<<BN, 512, 0, stream>>>(PRAW, PRAW2, temp, w_proj, MREP);
    // 6. fused (W*attn)*v via MFMA + IDWT -> fp32 out
    k_attnout_idwt<<<dim3(256, BN), 256, 0, stream>>>(VT, (const bfx8*)MREP, YH, out);
}